// Round 1
// baseline (270.222 us; speedup 1.0000x reference)
//
#include <hip/hip_runtime.h>
#include <hip/hip_bf16.h>

typedef __bf16 bf16_t;
typedef __bf16 bf16x8 __attribute__((ext_vector_type(8)));
typedef float f32x4 __attribute__((ext_vector_type(4)));

#define MFMA16(a, b, c) __builtin_amdgcn_mfma_f32_16x16x32_bf16((a), (b), (c), 0, 0, 0)

// Problem constants
// B=16, C=192, H=W=56, WIN=7, SHIFT=3, HEADS=6, DH=32, HID=768
// tokens M = 16*8*8*49 = 50176, windows = 1024

// ---------------- weight convert (4 weights -> contiguous bf16) ----------
__global__ __launch_bounds__(256) void k_cvt(const float* __restrict__ qkvw,
                                             const float* __restrict__ projw,
                                             const float* __restrict__ fc1w,
                                             const float* __restrict__ fc2w,
                                             bf16_t* __restrict__ dst)
{
    int i = blockIdx.x * 256 + threadIdx.x;
    if (i >= 442368) return;
    float v;
    if (i < 110592)      v = qkvw[i];
    else if (i < 147456) v = projw[i - 110592];
    else if (i < 294912) v = fc1w[i - 147456];
    else                 v = fc2w[i - 294912];
    dst[i] = (bf16_t)v;
}

// ---------------- LN1 + roll(-3) + window partition -> xw bf16 -----------
__global__ __launch_bounds__(256) void k_ln1(const float* __restrict__ x,
                                             const float* __restrict__ gam,
                                             const float* __restrict__ bet,
                                             bf16_t* __restrict__ xw)
{
    __shared__ float tile[192][57];   // pad 57: stride 228B -> 2-way max
    const int bh = blockIdx.x;        // b*56 + h
    const int b = bh / 56, h = bh % 56;
    const int tid = threadIdx.x, wave = tid >> 6, lane = tid & 63;
    const float* xbase = x + (long)b * 192 * 3136 + h * 56;
    for (int c = wave; c < 192; c += 4)
        if (lane < 56) tile[c][lane] = xbase[(long)c * 3136 + lane];
    __syncthreads();
    const int hr = (h + 53) % 56;     // rolled row index
    const int nh = hr / 7, ii = hr % 7;
    const float g0 = gam[lane], g1 = gam[lane + 64], g2 = gam[lane + 128];
    const float b0 = bet[lane], b1 = bet[lane + 64], b2 = bet[lane + 128];
    for (int wp = wave; wp < 56; wp += 4) {
        float v0 = tile[lane][wp], v1 = tile[lane + 64][wp], v2 = tile[lane + 128][wp];
        float s = v0 + v1 + v2;
        float sq = v0 * v0 + v1 * v1 + v2 * v2;
        #pragma unroll
        for (int d = 1; d < 64; d <<= 1) { s += __shfl_xor(s, d); sq += __shfl_xor(sq, d); }
        float mean = s * (1.f / 192.f);
        float var  = sq * (1.f / 192.f) - mean * mean;
        float rs = rsqrtf(var + 1e-5f);
        int wr = (wp + 53) % 56;
        int nw = wr / 7, jj = wr % 7;
        long r = (long)(b * 64 + nh * 8 + nw) * 49 + ii * 7 + jj;
        bf16_t* dst = xw + r * 192;
        dst[lane]       = (bf16_t)((v0 - mean) * rs * g0 + b0);
        dst[lane + 64]  = (bf16_t)((v1 - mean) * rs * g1 + b1);
        dst[lane + 128] = (bf16_t)((v2 - mean) * rs * g2 + b2);
    }
}

// ---------------- GEMM: out[M][N] = A[M][K] @ W[N][K]^T + bias -----------
// EPI: 0 = bf16 out, 1 = f32 out, 2 = bf16 out + exact GELU
template<int EPI>
__global__ __launch_bounds__(256) void k_gemm(const bf16_t* __restrict__ A,
                                              const bf16_t* __restrict__ W,
                                              const float* __restrict__ bias,
                                              void* __restrict__ outp,
                                              int M, int N, int K)
{
    __shared__ bf16_t As[128][72];  // +8 bf16 pad (keeps 16B alignment: 144B stride)
    __shared__ bf16_t Bs[64][72];
    const int tid = threadIdx.x;
    const int wave = tid >> 6, lane = tid & 63;
    const int lrow = lane & 15, lkg = lane >> 4;
    const int wm = (wave >> 1) * 64, wn = (wave & 1) * 32;
    const long m0 = (long)blockIdx.x * 128;
    const int n0 = blockIdx.y * 64;
    f32x4 acc[4][2];
    #pragma unroll
    for (int mi = 0; mi < 4; ++mi)
        #pragma unroll
        for (int ni = 0; ni < 2; ++ni)
            #pragma unroll
            for (int rg = 0; rg < 4; ++rg) acc[mi][ni][rg] = 0.f;

    for (int k0 = 0; k0 < K; k0 += 64) {
        #pragma unroll
        for (int it = 0; it < 4; ++it) {
            int e = (tid + it * 256) * 8;
            int r = e >> 6, c = e & 63;
            *(int4*)(&As[r][c]) = *(const int4*)(A + (m0 + r) * K + (k0 + c));
        }
        #pragma unroll
        for (int it = 0; it < 2; ++it) {
            int e = (tid + it * 256) * 8;
            int r = e >> 6, c = e & 63;
            *(int4*)(&Bs[r][c]) = *(const int4*)(W + (long)(n0 + r) * K + (k0 + c));
        }
        __syncthreads();
        #pragma unroll
        for (int kk = 0; kk < 64; kk += 32) {
            bf16x8 af[4], bfr[2];
            #pragma unroll
            for (int mi = 0; mi < 4; ++mi)
                af[mi] = *(const bf16x8*)(&As[wm + mi * 16 + lrow][kk + lkg * 8]);
            #pragma unroll
            for (int ni = 0; ni < 2; ++ni)
                bfr[ni] = *(const bf16x8*)(&Bs[wn + ni * 16 + lrow][kk + lkg * 8]);
            #pragma unroll
            for (int mi = 0; mi < 4; ++mi)
                #pragma unroll
                for (int ni = 0; ni < 2; ++ni)
                    acc[mi][ni] = MFMA16(af[mi], bfr[ni], acc[mi][ni]);
        }
        __syncthreads();
    }
    #pragma unroll
    for (int mi = 0; mi < 4; ++mi) {
        #pragma unroll
        for (int ni = 0; ni < 2; ++ni) {
            const int col = n0 + wn + ni * 16 + lrow;
            const float bv = bias[col];
            #pragma unroll
            for (int rg = 0; rg < 4; ++rg) {
                const long row = m0 + wm + mi * 16 + lkg * 4 + rg;
                float v = acc[mi][ni][rg] + bv;
                if (EPI == 2) v = 0.5f * v * (1.f + erff(v * 0.7071067811865475f));
                if (EPI == 1) ((float*)outp)[row * N + col] = v;
                else          ((bf16_t*)outp)[row * N + col] = (bf16_t)v;
            }
        }
    }
}

// ---------------- window attention: 1 wave per (window, head) ------------
__global__ __launch_bounds__(64) void k_attn(const bf16_t* __restrict__ qkv,
                                             bf16_t* __restrict__ aout)
{
    __shared__ bf16_t Pl[64][72];
    __shared__ bf16_t Vt[32][72];   // V transposed: Vt[d][m]
    const int win = blockIdx.x, head = blockIdx.y;
    const int lane = threadIdx.x;
    const int lrow = lane & 15, lkg = lane >> 4;
    const bf16_t* base = qkv + (long)win * 28224 + head * 32;  // 49*576

    // stage V^T into LDS (rows m>=49 zeroed)
    {
        const int m = lane;
        const int mc = (m < 49) ? m : 48;
        const int4* vr = (const int4*)(base + (long)mc * 576 + 384);
        #pragma unroll
        for (int c4 = 0; c4 < 4; ++c4) {
            int4 vv = vr[c4];
            if (m >= 49) vv = make_int4(0, 0, 0, 0);
            const bf16_t* pe = (const bf16_t*)&vv;
            #pragma unroll
            for (int e = 0; e < 8; ++e) Vt[c4 * 8 + e][m] = pe[e];
        }
    }

    // QK^T: S[n][m] = sum_d q[n][d] k[m][d], padded 49->64
    bf16x8 z8;
    #pragma unroll
    for (int e = 0; e < 8; ++e) z8[e] = (bf16_t)0.f;
    bf16x8 qf[4], kf[4];
    #pragma unroll
    for (int t = 0; t < 4; ++t) {
        const int n = t * 16 + lrow;
        const int nc = (n < 49) ? n : 48;
        bf16x8 qv = *(const bf16x8*)(base + (long)nc * 576 + lkg * 8);
        bf16x8 kv = *(const bf16x8*)(base + (long)nc * 576 + 192 + lkg * 8);
        qf[t] = (n < 49) ? qv : z8;
        kf[t] = (n < 49) ? kv : z8;
    }
    f32x4 zf; zf[0] = zf[1] = zf[2] = zf[3] = 0.f;
    f32x4 S[4][4];
    #pragma unroll
    for (int mi = 0; mi < 4; ++mi)
        #pragma unroll
        for (int mj = 0; mj < 4; ++mj)
            S[mi][mj] = MFMA16(qf[mi], kf[mj], zf);

    // row softmax (cols >= 49 masked), P -> LDS as bf16
    const float scl = 0.17677669529663687f;   // 32^-0.5
    #pragma unroll
    for (int mi = 0; mi < 4; ++mi) {
        #pragma unroll
        for (int rg = 0; rg < 4; ++rg) {
            float v0 = S[mi][0][rg] * scl;
            float v1 = S[mi][1][rg] * scl;
            float v2 = S[mi][2][rg] * scl;
            float v3 = (lrow == 0) ? S[mi][3][rg] * scl : -1e30f;  // col 48+lrow
            float mx = fmaxf(fmaxf(v0, v1), fmaxf(v2, v3));
            #pragma unroll
            for (int d = 1; d < 16; d <<= 1) mx = fmaxf(mx, __shfl_xor(mx, d));
            float e0 = expf(v0 - mx), e1 = expf(v1 - mx), e2 = expf(v2 - mx);
            float e3 = (lrow == 0) ? expf(v3 - mx) : 0.f;
            float sm = e0 + e1 + e2 + e3;
            #pragma unroll
            for (int d = 1; d < 16; d <<= 1) sm += __shfl_xor(sm, d);
            float is = 1.f / sm;
            const int row = mi * 16 + lkg * 4 + rg;
            Pl[row][lrow]      = (bf16_t)(e0 * is);
            Pl[row][16 + lrow] = (bf16_t)(e1 * is);
            Pl[row][32 + lrow] = (bf16_t)(e2 * is);
            Pl[row][48 + lrow] = (bf16_t)(e3 * is);
        }
    }
    __syncthreads();

    // PV: out[n][d] = sum_m P[n][m] Vt[d][m]
    f32x4 o[4][2];
    #pragma unroll
    for (int ni = 0; ni < 4; ++ni)
        #pragma unroll
        for (int di = 0; di < 2; ++di)
            #pragma unroll
            for (int rg = 0; rg < 4; ++rg) o[ni][di][rg] = 0.f;
    #pragma unroll
    for (int m0 = 0; m0 < 64; m0 += 32) {
        bf16x8 pf[4], vf[2];
        #pragma unroll
        for (int ni = 0; ni < 4; ++ni)
            pf[ni] = *(const bf16x8*)(&Pl[ni * 16 + lrow][m0 + lkg * 8]);
        #pragma unroll
        for (int di = 0; di < 2; ++di)
            vf[di] = *(const bf16x8*)(&Vt[di * 16 + lrow][m0 + lkg * 8]);
        #pragma unroll
        for (int ni = 0; ni < 4; ++ni)
            #pragma unroll
            for (int di = 0; di < 2; ++di)
                o[ni][di] = MFMA16(pf[ni], vf[di], o[ni][di]);
    }
    #pragma unroll
    for (int ni = 0; ni < 4; ++ni) {
        #pragma unroll
        for (int rg = 0; rg < 4; ++rg) {
            const int n = ni * 16 + lkg * 4 + rg;
            if (n < 49) {
                bf16_t* orow = aout + ((long)win * 49 + n) * 192 + head * 32;
                orow[lrow]      = (bf16_t)o[ni][0][rg];
                orow[16 + lrow] = (bf16_t)o[ni][1][rg];
            }
        }
    }
}

// ---------------- LN2 (per token row) -------------------------------------
__global__ __launch_bounds__(256) void k_ln2(const float* __restrict__ in,
                                             const float* __restrict__ gam,
                                             const float* __restrict__ bet,
                                             bf16_t* __restrict__ out)
{
    const long row = (long)blockIdx.x * 4 + (threadIdx.x >> 6);
    const int lane = threadIdx.x & 63;
    const float* r = in + row * 192;
    float v0 = r[lane], v1 = r[lane + 64], v2 = r[lane + 128];
    float s = v0 + v1 + v2, sq = v0 * v0 + v1 * v1 + v2 * v2;
    #pragma unroll
    for (int d = 1; d < 64; d <<= 1) { s += __shfl_xor(s, d); sq += __shfl_xor(sq, d); }
    float mean = s * (1.f / 192.f);
    float var  = sq * (1.f / 192.f) - mean * mean;
    float rs = rsqrtf(var + 1e-5f);
    bf16_t* o = out + row * 192;
    o[lane]       = (bf16_t)((v0 - mean) * rs * gam[lane]       + bet[lane]);
    o[lane + 64]  = (bf16_t)((v1 - mean) * rs * gam[lane + 64]  + bet[lane + 64]);
    o[lane + 128] = (bf16_t)((v2 - mean) * rs * gam[lane + 128] + bet[lane + 128]);
}

// ---------------- final: un-window + roll(+3) + BHWC->BCHW + shortcut ----
__global__ __launch_bounds__(256) void k_final(const float* __restrict__ f,
                                               const float* __restrict__ x,
                                               float* __restrict__ out)
{
    const long idx = (long)blockIdx.x * 256 + threadIdx.x;  // exact grid
    const int wq = (int)(idx % 56);
    long t = idx / 56;
    const int hq = (int)(t % 56); t /= 56;
    const int c = (int)(t % 192);
    const int b = (int)(t / 192);
    const int hr = (hq + 53) % 56, wr = (wq + 53) % 56;
    const int nh = hr / 7, ii = hr % 7, nw = wr / 7, jj = wr % 7;
    const long rrow = (long)(b * 64 + nh * 8 + nw) * 49 + ii * 7 + jj;
    out[idx] = f[rrow * 192 + c] + x[idx];
}

extern "C" void kernel_launch(void* const* d_in, const int* in_sizes, int n_in,
                              void* d_out, int out_size, void* d_ws, size_t ws_size,
                              hipStream_t stream)
{
    const float* x     = (const float*)d_in[0];
    const float* n1w   = (const float*)d_in[1];
    const float* n1b   = (const float*)d_in[2];
    const float* qkvw  = (const float*)d_in[3];
    const float* qkvb  = (const float*)d_in[4];
    const float* projw = (const float*)d_in[5];
    const float* projb = (const float*)d_in[6];
    const float* n2w   = (const float*)d_in[7];
    const float* n2b   = (const float*)d_in[8];
    const float* fc1w  = (const float*)d_in[9];
    const float* fc1b  = (const float*)d_in[10];
    const float* fc2w  = (const float*)d_in[11];
    const float* fc2b  = (const float*)d_in[12];

    char* ws = (char*)d_ws;
    // workspace layout (bytes), total 193,560,576
    bf16_t* wqkv  = (bf16_t*)(ws);             // 576*192  bf16
    bf16_t* wproj = (bf16_t*)(ws + 221184);    // 192*192
    bf16_t* wfc1  = (bf16_t*)(ws + 294912);    // 768*192
    bf16_t* wfc2  = (bf16_t*)(ws + 589824);    // 192*768
    bf16_t* Xb    = (bf16_t*)(ws + 884736);    // [50176][192] bf16 (reused 3x)
    bf16_t* QKV   = (bf16_t*)(ws + 20152320);  // [50176][576] bf16
    float*  F32B  = (float*) (ws + 77955072);  // [50176][192] f32  (reused 2x)
    bf16_t* Hb    = (bf16_t*)(ws + 116490240); // [50176][768] bf16

    k_cvt<<<1728, 256, 0, stream>>>(qkvw, projw, fc1w, fc2w, wqkv);
    k_ln1<<<896, 256, 0, stream>>>(x, n1w, n1b, Xb);
    k_gemm<0><<<dim3(392, 9), 256, 0, stream>>>(Xb, wqkv, qkvb, QKV, 50176, 576, 192);
    k_attn<<<dim3(1024, 6), 64, 0, stream>>>(QKV, Xb);
    k_gemm<1><<<dim3(392, 3), 256, 0, stream>>>(Xb, wproj, projb, F32B, 50176, 192, 192);
    k_ln2<<<12544, 256, 0, stream>>>(F32B, n2w, n2b, Xb);
    k_gemm<2><<<dim3(392, 12), 256, 0, stream>>>(Xb, wfc1, fc1b, Hb, 50176, 768, 192);
    k_gemm<1><<<dim3(392, 3), 256, 0, stream>>>(Hb, wfc2, fc2b, F32B, 50176, 192, 768);
    k_final<<<37632, 256, 0, stream>>>(F32B, x, (float*)d_out);
}

// Round 3
// 208.970 us; speedup vs baseline: 1.2931x; 1.2931x over previous
//
#include <hip/hip_runtime.h>
#include <hip/hip_bf16.h>

typedef __bf16 bf16_t;
typedef __bf16 bf16x8 __attribute__((ext_vector_type(8)));
typedef float f32x4 __attribute__((ext_vector_type(4)));

#define MFMA16(a, b, c) __builtin_amdgcn_mfma_f32_16x16x32_bf16((a), (b), (c), 0, 0, 0)

// Problem constants
// B=16, C=192, H=W=56, WIN=7, SHIFT=3, HEADS=6, DH=32, HID=768
// tokens M = 16*8*8*49 = 50176, windows = 1024

// ---------------- weight convert (4 weights -> contiguous bf16) ----------
__global__ __launch_bounds__(256) void k_cvt(const float* __restrict__ qkvw,
                                             const float* __restrict__ projw,
                                             const float* __restrict__ fc1w,
                                             const float* __restrict__ fc2w,
                                             bf16_t* __restrict__ dst)
{
    int i = blockIdx.x * 256 + threadIdx.x;
    if (i >= 442368) return;
    float v;
    if (i < 110592)      v = qkvw[i];
    else if (i < 147456) v = projw[i - 110592];
    else if (i < 294912) v = fc1w[i - 147456];
    else                 v = fc2w[i - 294912];
    dst[i] = (bf16_t)v;
}

// ---------------- LN1 + roll(-3) + window partition -> xw bf16 -----------
// block = (b, h); tile[w][c] transposed stage, obuf staged int4 stores
__global__ __launch_bounds__(1024) void k_ln1(const float* __restrict__ x,
                                              const float* __restrict__ gam,
                                              const float* __restrict__ bet,
                                              bf16_t* __restrict__ xw)
{
    __shared__ float tile[56][193];     // odd stride: conflict-free row reads
    __shared__ bf16_t obuf[56 * 192];   // row stride 384B = 24 int4
    const int bh = blockIdx.x;
    const int b = bh / 56, h = bh % 56;
    const int tid = threadIdx.x;

    // phase 1: x[b][:][h][:] -> tile[w][c] (float4 global loads)
    {
        const int g = tid >> 4, u = tid & 15;   // g: channel group 0..63
        const float* xb = x + (long)b * 602112 + (long)h * 56;
        if (u < 14) {
            #pragma unroll
            for (int k = 0; k < 3; ++k) {
                const int c = g + 64 * k;
                float4 v = *(const float4*)(xb + (long)c * 3136 + u * 4);
                tile[u * 4 + 0][c] = v.x;
                tile[u * 4 + 1][c] = v.y;
                tile[u * 4 + 2][c] = v.z;
                tile[u * 4 + 3][c] = v.w;
            }
        }
    }
    __syncthreads();

    // phase 2: LN per token (wave-parallel over w), bf16 -> obuf by rolled idx
    const int wave = tid >> 6, lane = tid & 63;
    const float g0 = gam[lane], g1 = gam[lane + 64], g2 = gam[lane + 128];
    const float b0 = bet[lane], b1 = bet[lane + 64], b2 = bet[lane + 128];
    for (int wp = wave; wp < 56; wp += 16) {
        float v0 = tile[wp][lane], v1 = tile[wp][lane + 64], v2 = tile[wp][lane + 128];
        float s = v0 + v1 + v2;
        float sq = v0 * v0 + v1 * v1 + v2 * v2;
        #pragma unroll
        for (int d = 1; d < 64; d <<= 1) { s += __shfl_xor(s, d); sq += __shfl_xor(sq, d); }
        float mean = s * (1.f / 192.f);
        float var  = sq * (1.f / 192.f) - mean * mean;
        float rs = rsqrtf(var + 1e-5f);
        const int wr = (wp + 53) % 56;
        bf16_t* o = obuf + wr * 192;
        o[lane]       = (bf16_t)((v0 - mean) * rs * g0 + b0);
        o[lane + 64]  = (bf16_t)((v1 - mean) * rs * g1 + b1);
        o[lane + 128] = (bf16_t)((v2 - mean) * rs * g2 + b2);
    }
    __syncthreads();

    // phase 3: obuf -> xw, 8 window-groups x 7 contiguous rows (int4 stores)
    const int hr = (h + 53) % 56;
    const int nh = hr / 7, ii = hr % 7;
    const long rband = ((long)b * 64 + (long)nh * 8) * 49 + (long)ii * 7;
    const int4* src = (const int4*)obuf;
    for (int q = tid; q < 1344; q += 1024) {
        const int g = q / 168, u = q % 168;
        const int jj = u / 24, ci = u % 24;
        const long r = rband + (long)g * 49 + jj;
        ((int4*)xw)[r * 24 + ci] = src[(g * 7 + jj) * 24 + ci];
    }
}

// ---------------- GEMM: out[M][N] = A[M][K] @ W[N][K]^T + bias -----------
// EPI: 0 = bf16 out, 1 = f32 out, 2 = bf16 out + exact GELU
template<int EPI>
__global__ __launch_bounds__(256) void k_gemm(const bf16_t* __restrict__ A,
                                              const bf16_t* __restrict__ W,
                                              const float* __restrict__ bias,
                                              void* __restrict__ outp,
                                              int M, int N, int K)
{
    __shared__ bf16_t As[128][72];  // +8 bf16 pad (keeps 16B alignment: 144B stride)
    __shared__ bf16_t Bs[64][72];
    const int tid = threadIdx.x;
    const int wave = tid >> 6, lane = tid & 63;
    const int lrow = lane & 15, lkg = lane >> 4;
    const int wm = (wave >> 1) * 64, wn = (wave & 1) * 32;
    const long m0 = (long)blockIdx.x * 128;
    const int n0 = blockIdx.y * 64;
    f32x4 acc[4][2];
    #pragma unroll
    for (int mi = 0; mi < 4; ++mi)
        #pragma unroll
        for (int ni = 0; ni < 2; ++ni)
            #pragma unroll
            for (int rg = 0; rg < 4; ++rg) acc[mi][ni][rg] = 0.f;

    for (int k0 = 0; k0 < K; k0 += 64) {
        #pragma unroll
        for (int it = 0; it < 4; ++it) {
            int e = (tid + it * 256) * 8;
            int r = e >> 6, c = e & 63;
            *(int4*)(&As[r][c]) = *(const int4*)(A + (m0 + r) * K + (k0 + c));
        }
        #pragma unroll
        for (int it = 0; it < 2; ++it) {
            int e = (tid + it * 256) * 8;
            int r = e >> 6, c = e & 63;
            *(int4*)(&Bs[r][c]) = *(const int4*)(W + (long)(n0 + r) * K + (k0 + c));
        }
        __syncthreads();
        #pragma unroll
        for (int kk = 0; kk < 64; kk += 32) {
            bf16x8 af[4], bfr[2];
            #pragma unroll
            for (int mi = 0; mi < 4; ++mi)
                af[mi] = *(const bf16x8*)(&As[wm + mi * 16 + lrow][kk + lkg * 8]);
            #pragma unroll
            for (int ni = 0; ni < 2; ++ni)
                bfr[ni] = *(const bf16x8*)(&Bs[wn + ni * 16 + lrow][kk + lkg * 8]);
            #pragma unroll
            for (int mi = 0; mi < 4; ++mi)
                #pragma unroll
                for (int ni = 0; ni < 2; ++ni)
                    acc[mi][ni] = MFMA16(af[mi], bfr[ni], acc[mi][ni]);
        }
        __syncthreads();
    }
    #pragma unroll
    for (int mi = 0; mi < 4; ++mi) {
        #pragma unroll
        for (int ni = 0; ni < 2; ++ni) {
            const int col = n0 + wn + ni * 16 + lrow;
            const float bv = bias[col];
            #pragma unroll
            for (int rg = 0; rg < 4; ++rg) {
                const long row = m0 + wm + mi * 16 + lkg * 4 + rg;
                float v = acc[mi][ni][rg] + bv;
                if (EPI == 2) v = 0.5f * v * (1.f + erff(v * 0.7071067811865475f));
                if (EPI == 1) ((float*)outp)[row * N + col] = v;
                else          ((bf16_t*)outp)[row * N + col] = (bf16_t)v;
            }
        }
    }
}

// ---------------- window attention: 1 wave per (window, head) ------------
__global__ __launch_bounds__(64) void k_attn(const bf16_t* __restrict__ qkv,
                                             bf16_t* __restrict__ aout)
{
    __shared__ bf16_t Pl[64][72];
    __shared__ bf16_t Vt[32][72];   // V transposed: Vt[d][m]
    const int win = blockIdx.x, head = blockIdx.y;
    const int lane = threadIdx.x;
    const int lrow = lane & 15, lkg = lane >> 4;
    const bf16_t* base = qkv + (long)win * 28224 + head * 32;  // 49*576

    // stage V^T into LDS (rows m>=49 zeroed)
    {
        const int m = lane;
        const int mc = (m < 49) ? m : 48;
        const int4* vr = (const int4*)(base + (long)mc * 576 + 384);
        #pragma unroll
        for (int c4 = 0; c4 < 4; ++c4) {
            int4 vv = vr[c4];
            if (m >= 49) vv = make_int4(0, 0, 0, 0);
            const bf16_t* pe = (const bf16_t*)&vv;
            #pragma unroll
            for (int e = 0; e < 8; ++e) Vt[c4 * 8 + e][m] = pe[e];
        }
    }

    // QK^T: S[n][m] = sum_d q[n][d] k[m][d], padded 49->64
    bf16x8 z8;
    #pragma unroll
    for (int e = 0; e < 8; ++e) z8[e] = (bf16_t)0.f;
    bf16x8 qf[4], kf[4];
    #pragma unroll
    for (int t = 0; t < 4; ++t) {
        const int n = t * 16 + lrow;
        const int nc = (n < 49) ? n : 48;
        bf16x8 qv = *(const bf16x8*)(base + (long)nc * 576 + lkg * 8);
        bf16x8 kv = *(const bf16x8*)(base + (long)nc * 576 + 192 + lkg * 8);
        qf[t] = (n < 49) ? qv : z8;
        kf[t] = (n < 49) ? kv : z8;
    }
    f32x4 zf; zf[0] = zf[1] = zf[2] = zf[3] = 0.f;
    f32x4 S[4][4];
    #pragma unroll
    for (int mi = 0; mi < 4; ++mi)
        #pragma unroll
        for (int mj = 0; mj < 4; ++mj)
            S[mi][mj] = MFMA16(qf[mi], kf[mj], zf);

    // row softmax (cols >= 49 masked), P -> LDS as bf16
    const float scl = 0.17677669529663687f;   // 32^-0.5
    #pragma unroll
    for (int mi = 0; mi < 4; ++mi) {
        #pragma unroll
        for (int rg = 0; rg < 4; ++rg) {
            float v0 = S[mi][0][rg] * scl;
            float v1 = S[mi][1][rg] * scl;
            float v2 = S[mi][2][rg] * scl;
            float v3 = (lrow == 0) ? S[mi][3][rg] * scl : -1e30f;  // col 48+lrow
            float mx = fmaxf(fmaxf(v0, v1), fmaxf(v2, v3));
            #pragma unroll
            for (int d = 1; d < 16; d <<= 1) mx = fmaxf(mx, __shfl_xor(mx, d));
            float e0 = expf(v0 - mx), e1 = expf(v1 - mx), e2 = expf(v2 - mx);
            float e3 = (lrow == 0) ? expf(v3 - mx) : 0.f;
            float sm = e0 + e1 + e2 + e3;
            #pragma unroll
            for (int d = 1; d < 16; d <<= 1) sm += __shfl_xor(sm, d);
            float is = 1.f / sm;
            const int row = mi * 16 + lkg * 4 + rg;
            Pl[row][lrow]      = (bf16_t)(e0 * is);
            Pl[row][16 + lrow] = (bf16_t)(e1 * is);
            Pl[row][32 + lrow] = (bf16_t)(e2 * is);
            Pl[row][48 + lrow] = (bf16_t)(e3 * is);
        }
    }
    __syncthreads();

    // PV: out[n][d] = sum_m P[n][m] Vt[d][m]
    f32x4 o[4][2];
    #pragma unroll
    for (int ni = 0; ni < 4; ++ni)
        #pragma unroll
        for (int di = 0; di < 2; ++di)
            #pragma unroll
            for (int rg = 0; rg < 4; ++rg) o[ni][di][rg] = 0.f;
    #pragma unroll
    for (int m0 = 0; m0 < 64; m0 += 32) {
        bf16x8 pf[4], vf[2];
        #pragma unroll
        for (int ni = 0; ni < 4; ++ni)
            pf[ni] = *(const bf16x8*)(&Pl[ni * 16 + lrow][m0 + lkg * 8]);
        #pragma unroll
        for (int di = 0; di < 2; ++di)
            vf[di] = *(const bf16x8*)(&Vt[di * 16 + lrow][m0 + lkg * 8]);
        #pragma unroll
        for (int ni = 0; ni < 4; ++ni)
            #pragma unroll
            for (int di = 0; di < 2; ++di)
                o[ni][di] = MFMA16(pf[ni], vf[di], o[ni][di]);
    }
    #pragma unroll
    for (int ni = 0; ni < 4; ++ni) {
        #pragma unroll
        for (int rg = 0; rg < 4; ++rg) {
            const int n = ni * 16 + lkg * 4 + rg;
            if (n < 49) {
                bf16_t* orow = aout + ((long)win * 49 + n) * 192 + head * 32;
                orow[lrow]      = (bf16_t)o[ni][0][rg];
                orow[16 + lrow] = (bf16_t)o[ni][1][rg];
            }
        }
    }
}

// ---------------- LN2 (per token row), int4 staged stores -----------------
__global__ __launch_bounds__(256) void k_ln2(const float* __restrict__ in,
                                             const float* __restrict__ gam,
                                             const float* __restrict__ bet,
                                             bf16_t* __restrict__ out)
{
    __shared__ bf16_t ob[4 * 192];
    const long row0 = (long)blockIdx.x * 4;
    const int wave = threadIdx.x >> 6, lane = threadIdx.x & 63;
    const float* r = in + (row0 + wave) * 192;
    float v0 = r[lane], v1 = r[lane + 64], v2 = r[lane + 128];
    float s = v0 + v1 + v2, sq = v0 * v0 + v1 * v1 + v2 * v2;
    #pragma unroll
    for (int d = 1; d < 64; d <<= 1) { s += __shfl_xor(s, d); sq += __shfl_xor(sq, d); }
    float mean = s * (1.f / 192.f);
    float var  = sq * (1.f / 192.f) - mean * mean;
    float rs = rsqrtf(var + 1e-5f);
    bf16_t* o = ob + wave * 192;
    o[lane]       = (bf16_t)((v0 - mean) * rs * gam[lane]       + bet[lane]);
    o[lane + 64]  = (bf16_t)((v1 - mean) * rs * gam[lane + 64]  + bet[lane + 64]);
    o[lane + 128] = (bf16_t)((v2 - mean) * rs * gam[lane + 128] + bet[lane + 128]);
    __syncthreads();
    if (threadIdx.x < 96)
        ((int4*)(out + row0 * 192))[threadIdx.x] = ((const int4*)ob)[threadIdx.x];
}

// ---------------- final: un-window + roll(+3) + BHWC->BCHW + shortcut ----
// block = (b, hq); coalesced f reads, coalesced out/x along w
__global__ __launch_bounds__(1024) void k_final(const float* __restrict__ f,
                                                const float* __restrict__ x,
                                                float* __restrict__ out)
{
    __shared__ float tile[56][199];   // odd-ish stride 199: conflict-free col reads
    const int bh = blockIdx.x;
    const int b = bh / 56, hq = bh % 56;
    const int tid = threadIdx.x;
    const int hr = (hq + 53) % 56;
    const int nh = hr / 7, ii = hr % 7;
    const long rband = ((long)b * 64 + (long)nh * 8) * 49 + (long)ii * 7;

    // phase 1: gather f rows (coalesced 5376B chunks) into tile[wq][c]
    for (int q = tid; q < 2688; q += 1024) {
        const int g = q / 336, rem = q % 336;
        const int jj = rem / 48, c4 = rem % 48;
        const long rr = rband + (long)g * 49 + jj;
        float4 v = *(const float4*)(f + rr * 192 + c4 * 4);
        const int wq = (g * 7 + jj + 3) % 56;
        tile[wq][c4 * 4 + 0] = v.x;
        tile[wq][c4 * 4 + 1] = v.y;
        tile[wq][c4 * 4 + 2] = v.z;
        tile[wq][c4 * 4 + 3] = v.w;
    }
    __syncthreads();

    // phase 2: out[b][c][hq][w] = tile[w][c] + x[b][c][hq][w]  (float4 along w)
    const int g = tid >> 4, u = tid & 15;
    if (u < 14) {
        #pragma unroll
        for (int k = 0; k < 3; ++k) {
            const int c = g + 64 * k;
            const long base = ((long)b * 192 + c) * 3136 + (long)hq * 56 + u * 4;
            float4 xv = *(const float4*)(x + base);
            float4 ov;
            ov.x = tile[u * 4 + 0][c] + xv.x;
            ov.y = tile[u * 4 + 1][c] + xv.y;
            ov.z = tile[u * 4 + 2][c] + xv.z;
            ov.w = tile[u * 4 + 3][c] + xv.w;
            *(float4*)(out + base) = ov;
        }
    }
}

extern "C" void kernel_launch(void* const* d_in, const int* in_sizes, int n_in,
                              void* d_out, int out_size, void* d_ws, size_t ws_size,
                              hipStream_t stream)
{
    const float* x     = (const float*)d_in[0];
    const float* n1w   = (const float*)d_in[1];
    const float* n1b   = (const float*)d_in[2];
    const float* qkvw  = (const float*)d_in[3];
    const float* qkvb  = (const float*)d_in[4];
    const float* projw = (const float*)d_in[5];
    const float* projb = (const float*)d_in[6];
    const float* n2w   = (const float*)d_in[7];
    const float* n2b   = (const float*)d_in[8];
    const float* fc1w  = (const float*)d_in[9];
    const float* fc1b  = (const float*)d_in[10];
    const float* fc2w  = (const float*)d_in[11];
    const float* fc2b  = (const float*)d_in[12];

    char* ws = (char*)d_ws;
    // workspace layout (bytes), total 193,560,576
    bf16_t* wqkv  = (bf16_t*)(ws);             // 576*192  bf16
    bf16_t* wproj = (bf16_t*)(ws + 221184);    // 192*192
    bf16_t* wfc1  = (bf16_t*)(ws + 294912);    // 768*192
    bf16_t* wfc2  = (bf16_t*)(ws + 589824);    // 192*768
    bf16_t* Xb    = (bf16_t*)(ws + 884736);    // [50176][192] bf16 (reused 3x)
    bf16_t* QKV   = (bf16_t*)(ws + 20152320);  // [50176][576] bf16
    float*  F32B  = (float*) (ws + 77955072);  // [50176][192] f32  (reused 2x)
    bf16_t* Hb    = (bf16_t*)(ws + 116490240); // [50176][768] bf16

    k_cvt<<<1728, 256, 0, stream>>>(qkvw, projw, fc1w, fc2w, wqkv);
    k_ln1<<<896, 1024, 0, stream>>>(x, n1w, n1b, Xb);
    k_gemm<0><<<dim3(392, 9), 256, 0, stream>>>(Xb, wqkv, qkvb, QKV, 50176, 576, 192);
    k_attn<<<dim3(1024, 6), 64, 0, stream>>>(QKV, Xb);
    k_gemm<1><<<dim3(392, 3), 256, 0, stream>>>(Xb, wproj, projb, F32B, 50176, 192, 192);
    k_ln2<<<12544, 256, 0, stream>>>(F32B, n2w, n2b, Xb);
    k_gemm<2><<<dim3(392, 12), 256, 0, stream>>>(Xb, wfc1, fc1b, Hb, 50176, 768, 192);
    k_gemm<1><<<dim3(392, 3), 256, 0, stream>>>(Hb, wfc2, fc2b, F32B, 50176, 192, 768);
    k_final<<<896, 1024, 0, stream>>>(F32B, x, (float*)d_out);
}